// Round 7
// baseline (206.769 us; speedup 1.0000x reference)
//
#include <hip/hip_runtime.h>
#include <hip/hip_cooperative_groups.h>
#include <hip/hip_bf16.h>
#include <math.h>

namespace cg = cooperative_groups;

#define LEN_M   131328
#define D_P1    513
#define NROW    4096
#define PRED_ELEMS (NROW * 64)            // 262144

// ws layout: wcbt bf16 [512 c][512 k], XOR-swizzled 16B chunks (512 KB).
typedef __attribute__((ext_vector_type(8))) short short8;     // 8 bf16 = 4 VGPR
typedef __attribute__((ext_vector_type(4))) float floatx4;    // mfma acc
typedef __attribute__((ext_vector_type(2))) float v2f;        // packed fp32

__device__ __forceinline__ void gl_lds16(const void* g, void* l)
{
    __builtin_amdgcn_global_load_lds(
        (const __attribute__((address_space(1))) unsigned int*)g,
        (__attribute__((address_space(3))) unsigned int*)l, 16, 0, 0);
}

__device__ __forceinline__ unsigned short bf16b(float f)
{
    __hip_bfloat16 h = __float2bfloat16(f);
    return *(unsigned short*)&h;
}

// ----------------------------------------------------------------- fused ----
// ONE cooperative kernel, grid = 512 blocks (2/CU co-resident).
// Phase 1: blocks 0..63 build swizzled wcbt; blocks 64..511 zero pred + write
//          m_w0/v_w0. ALL blocks stage their 32x512 A-panel (x->bf16) to LDS.
// grid.sync()
// Phase 2: H = bid&3, bm = (bid>>2)*32 — B double-buffered via global_load_lds,
//          16x16x32 bf16 MFMA, k=512 fp32 fixup, LDS C-tile, pred epilogue,
//          atomic accumulate into out.
__global__ __launch_bounds__(256) void fused_kernel(
    const float* __restrict__ params, const float* __restrict__ x,
    const float* __restrict__ W1, const float* __restrict__ eps,
    float* __restrict__ out, __hip_bfloat16* __restrict__ wcbt)
{
    __shared__ char smem[49152];
    char*  Bs   = smem;                                  // 2 x [128 lc][32 k] 16 KB
    char*  As   = smem + 16384;                          // [32 r][512 k]     32 KB
    float* Clds = (float*)(smem + 16384);                // [128 lc][36] (alias A)
    unsigned short (*T)[65] = (unsigned short (*)[65])smem;  // phase-1 alias (8.3 KB)

    const int bid = blockIdx.x;
    const int t   = threadIdx.x;
    const int w4 = t >> 6, lane = t & 63;
    const int lane15 = lane & 15, quad = lane >> 4;
    const int H  = bid & 3;                              // h-range [H*64, +64)
    const int bm = (bid >> 2) * 32;

    // ================= phase 1 =================
    if (bid < 64) {
        // ---- build swizzled wcbt[c][k] bf16 via LDS transpose (64 blocks)
        const int k0 = (bid & 7) * 64;
        const int c0 = (bid >> 3) * 64;
        const int hh = t & 63, kb = t >> 6;
        const bool spart = (c0 >= 256);
        const int hbase = c0 & 255;
        const float* src = params + (spart ? LEN_M : 0);

        #pragma unroll 4
        for (int p = 0; p < 16; ++p) {
            int kk = p * 4 + kb;
            float v = src[(k0 + kk) * 256 + hbase + hh];
            if (spart) v = sqrtf(fmaxf(v, 0.0f) + 1e-6f);
            T[kk][hh] = bf16b(v);
        }
        __syncthreads();

        const int cc = t >> 2, kq = t & 3;
        short8 lo, hi;
        #pragma unroll
        for (int j = 0; j < 8; ++j) lo[j] = (short)T[kq * 16 + j][cc];
        #pragma unroll
        for (int j = 0; j < 8; ++j) hi[j] = (short)T[kq * 16 + 8 + j][cc];

        const int cR  = c0 + cc;
        const int swz = (cR >> 1) & 3;
        const int g1  = (k0 >> 3) + 2 * kq;              // 16B-chunk idx in row
        const int g2  = g1 + 1;
        const int d1  = cR * 64 + (g1 & ~3) + ((g1 & 3) ^ swz);
        const int d2  = cR * 64 + (g2 & ~3) + ((g2 & 3) ^ swz);
        short* wb = (short*)wcbt;
        *(short8*)(wb + d1 * 8) = lo;
        *(short8*)(wb + d2 * 8) = hi;
        __syncthreads();                                 // T reads done (Bs reused ph2)
    } else {
        // ---- zero pred region + write m_w0 / v_w0 (448 blocks)
        const int j = (bid - 64) * 256 + t;
        if (j < 65536) {
            float4 z = {0.f, 0.f, 0.f, 0.f};
            *(float4*)(out + j * 4) = z;
        }
        for (int i = j; i < LEN_M; i += 448 * 256) {
            float m = params[i];
            float v = fmaxf(params[LEN_M + i], 0.0f) + 1e-6f;
            out[PRED_ELEMS + i]         = m;             // m_w0
            out[PRED_ELEMS + LEN_M + i] = v;             // v_w0
        }
    }

    // ---- A panel staging (ALL blocks): [32 r][512 k] bf16, XOR-swizzled
    {
        const int ar = t >> 3, a8 = t & 7;
        const float* axp = x + (bm + ar) * D_P1;
        unsigned short* arow = (unsigned short*)As + ar * 512;
        #pragma unroll 4
        for (int ks = 0; ks < 16; ++ks) {
            int k = ks * 32 + a8 * 4;
            float f0 = axp[k], f1 = axp[k + 1], f2 = axp[k + 2], f3 = axp[k + 3];
            int chunk = k >> 3;
            int half  = a8 & 1;
            int cs = (chunk & ~7) | ((chunk & 7) ^ (ar & 7));
            ushort4 pk;
            pk.x = bf16b(f0); pk.y = bf16b(f1); pk.z = bf16b(f2); pk.w = bf16b(f3);
            *(ushort4*)(arow + cs * 8 + half * 4) = pk;
        }
    }

    // ---- early independent loads (k=512 fixup + eps + wl)
    const float e = eps[lane];
    float xl[2][4];
    #pragma unroll
    for (int rh = 0; rh < 2; ++rh)
        #pragma unroll
        for (int i = 0; i < 4; ++i)
            xl[rh][i] = x[(bm + rh * 16 + quad * 4 + i) * D_P1 + 512];
    float wl[2];
    #pragma unroll
    for (int s = 0; s < 2; ++s) {
        int lc = w4 * 32 + s * 16 + lane15;
        int c  = H * 64 + lc + ((lc >> 6) * 192);
        wl[s] = (c < 256) ? params[131072 + c]
                          : sqrtf(fmaxf(params[LEN_M + 131072 + (c - 256)], 0.0f) + 1e-6f);
    }

    __threadfence();                                     // wcbt / out-zero visible
    cg::this_grid().sync();

    // ================= phase 2 =================
    // ---- B staging source/dest (identity copy; swizzle pre-baked in wcbt)
    const short* wb = (const short*)wcbt;
    const short* bsrc0; const short* bsrc1;
    {
        int ch0 = t, ch1 = 256 + t;
        int lc0 = ch0 >> 2, qs0 = ch0 & 3;
        int lc1 = ch1 >> 2, qs1 = ch1 & 3;
        int c0g = H * 64 + lc0 + ((lc0 >> 6) * 192);
        int c1g = H * 64 + lc1 + ((lc1 >> 6) * 192);
        bsrc0 = wb + (c0g * 64 + qs0) * 8;
        bsrc1 = wb + (c1g * 64 + qs1) * 8;
    }
    char* bd0 = Bs + t * 16;
    char* bd1 = Bs + 4096 + t * 16;

    // pre-stage B slice 0 into buf 0
    gl_lds16(bsrc0, bd0);
    gl_lds16(bsrc1, bd1);

    // ---- B fragment byte offsets (within a buffer)
    int bfo[2];
    #pragma unroll
    for (int s = 0; s < 2; ++s) {
        int lc = w4 * 32 + s * 16 + lane15;
        bfo[s] = lc * 64 + ((quad ^ ((lc >> 1) & 3)) * 16);
    }
    const int ax7 = lane15 & 7;

    floatx4 acc00 = {0.f,0.f,0.f,0.f}, acc01 = acc00, acc10 = acc00, acc11 = acc00;

    __syncthreads();                                     // B slice 0 ready

    for (int ks = 0; ks < 16; ++ks) {
        // prefetch B slice ks+1 into other buffer (iter 15: harmless overread)
        const int nb = (ks + 1) & 1;
        gl_lds16(bsrc0 + (ks + 1) * 32, bd0 + nb * 8192);
        gl_lds16(bsrc1 + (ks + 1) * 32, bd1 + nb * 8192);

        // A frags: row-major swizzled panel
        const int cs16 = ((ks >> 1) * 8 + (((ks & 1) * 4 + quad) ^ ax7)) * 16;
        short8 a0 = *(const short8*)(As + lane15 * 1024 + cs16);
        short8 a1 = *(const short8*)(As + (16 + lane15) * 1024 + cs16);
        // B frags from current buffer
        const char* Bb = Bs + (ks & 1) * 8192;
        short8 b0 = *(const short8*)(Bb + bfo[0]);
        short8 b1 = *(const short8*)(Bb + bfo[1]);

        acc00 = __builtin_amdgcn_mfma_f32_16x16x32_bf16(a0, b0, acc00, 0, 0, 0);
        acc01 = __builtin_amdgcn_mfma_f32_16x16x32_bf16(a0, b1, acc01, 0, 0, 0);
        acc10 = __builtin_amdgcn_mfma_f32_16x16x32_bf16(a1, b0, acc10, 0, 0, 0);
        acc11 = __builtin_amdgcn_mfma_f32_16x16x32_bf16(a1, b1, acc11, 0, 0, 0);
        __syncthreads();                                 // next buffer staged & safe
    }

    // ---- fixup k=512 + C -> LDS [lc][r] (aliases A panel; all A reads done)
    floatx4 accs[2][2] = {{acc00, acc01}, {acc10, acc11}};
    #pragma unroll
    for (int rh = 0; rh < 2; ++rh)
        #pragma unroll
        for (int s = 0; s < 2; ++s) {
            float4 o;
            o.x = accs[rh][s][0] + xl[rh][0] * wl[s];
            o.y = accs[rh][s][1] + xl[rh][1] * wl[s];
            o.z = accs[rh][s][2] + xl[rh][2] * wl[s];
            o.w = accs[rh][s][3] + xl[rh][3] * wl[s];
            int lc = w4 * 32 + s * 16 + lane15;
            int r0 = rh * 16 + quad * 4;
            *(float4*)&Clds[lc * 36 + r0] = o;
        }
    __syncthreads();

    // ---- pred epilogue: lane = m; wave w4 rows rb..rb+7; packed fp32 math
    const int rb = w4 * 8;
    const float binit = (H == 0) ? W1[0] : 0.0f;
    v2f accp[4];
    #pragma unroll
    for (int j = 0; j < 4; ++j) accp[j] = (v2f){binit, binit};
    const v2f e2 = {e, e};
    const v2f z2 = {0.f, 0.f};

    #pragma unroll 4
    for (int lh = 0; lh < 64; ++lh) {
        const float w1h = W1[1 + H * 64 + lh];
        const v2f w2 = {w1h, w1h};
        const v2f* ap = (const v2f*)&Clds[lh * 36 + rb];
        const v2f* bp = (const v2f*)&Clds[(64 + lh) * 36 + rb];
        #pragma unroll
        for (int j = 0; j < 4; ++j) {
            v2f t2 = __builtin_elementwise_fma(e2, bp[j], ap[j]);
            t2 = __builtin_elementwise_max(t2, z2);
            accp[j] = __builtin_elementwise_fma(t2, w2, accp[j]);
        }
    }

    float* op = out + (bm + rb) * 64 + lane;
    #pragma unroll
    for (int j = 0; j < 4; ++j) {
        unsafeAtomicAdd(op + (2 * j) * 64,     accp[j].x);
        unsafeAtomicAdd(op + (2 * j + 1) * 64, accp[j].y);
    }
}

// -------------------------------------------------------------- launch ------
extern "C" void kernel_launch(void* const* d_in, const int* in_sizes, int n_in,
                              void* d_out, int out_size, void* d_ws, size_t ws_size,
                              hipStream_t stream)
{
    const float* params = (const float*)d_in[0];
    const float* W1     = (const float*)d_in[1];
    const float* x      = (const float*)d_in[2];
    const float* eps    = (const float*)d_in[3];
    float* out = (float*)d_out;
    __hip_bfloat16* wcbt = (__hip_bfloat16*)d_ws;

    void* args[] = {(void*)&params, (void*)&x, (void*)&W1, (void*)&eps,
                    (void*)&out, (void*)&wcbt};
    hipLaunchCooperativeKernel((const void*)fused_kernel, dim3(512), dim3(256),
                               args, 0, stream);
}

// Round 8
// 84.434 us; speedup vs baseline: 2.4489x; 2.4489x over previous
//
#include <hip/hip_runtime.h>
#include <hip/hip_bf16.h>
#include <math.h>

#define LEN_M   131328
#define D_P1    513
#define NROW    4096
#define PRED_ELEMS (NROW * 64)            // 262144

// ws: wcbt bf16, 512 KB: 8 k-chunks (kc) of 64 KB; each is the LDS image
// [512 c][64 k] with 16B-chunk swizzle g' = g ^ (c&7)  (g = k/8 within kc).
// chunk_idx(c, g, kc) = kc*4096 + c*8 + (g ^ (c&7))
typedef __attribute__((ext_vector_type(8))) short short8;     // 8 bf16 = 4 VGPR
typedef __attribute__((ext_vector_type(4))) float floatx4;    // mfma acc
typedef __attribute__((ext_vector_type(2))) float v2f;        // packed fp32

__device__ __forceinline__ void gl_lds16(const void* g, void* l)
{
    __builtin_amdgcn_global_load_lds(
        (const __attribute__((address_space(1))) unsigned int*)g,
        (__attribute__((address_space(3))) unsigned int*)l, 16, 0, 0);
}

__device__ __forceinline__ unsigned short bf16b(float f)
{
    __hip_bfloat16 h = __float2bfloat16(f);
    return *(unsigned short*)&h;
}

// ------------------------------------------------------------------ prep ----
// blocks [0,513): m_w0 / v_w0 outputs (513*256 == LEN_M exactly)
// blocks [513,577): build swizzled wcbt via LDS transpose
__global__ __launch_bounds__(256) void prep_kernel(
    const float* __restrict__ params, float* __restrict__ out,
    __hip_bfloat16* __restrict__ wcbt)
{
    __shared__ unsigned short T[64][65];
    const int bid = blockIdx.x;
    const int t   = threadIdx.x;

    if (bid < 513) {
        int i = bid * 256 + t;
        float m = params[i];
        float v = fmaxf(params[LEN_M + i], 0.0f) + 1e-6f;
        out[PRED_ELEMS + i]         = m;                 // m_w0
        out[PRED_ELEMS + LEN_M + i] = v;                 // v_w0
        return;
    }

    const int b2 = bid - 513;
    const int k0 = (b2 & 7) * 64;
    const int c0 = (b2 >> 3) * 64;
    const int hh = t & 63, kb = t >> 6;
    const bool spart = (c0 >= 256);
    const int hbase = c0 & 255;
    const float* src = params + (spart ? LEN_M : 0);

    #pragma unroll 4
    for (int p = 0; p < 16; ++p) {
        int kk = p * 4 + kb;
        float v = src[(k0 + kk) * 256 + hbase + hh];
        if (spart) v = sqrtf(fmaxf(v, 0.0f) + 1e-6f);
        T[kk][hh] = bf16b(v);
    }
    __syncthreads();

    const int cc = t >> 2, kq = t & 3;
    short8 lo, hi;
    #pragma unroll
    for (int j = 0; j < 8; ++j) lo[j] = (short)T[kq * 16 + j][cc];
    #pragma unroll
    for (int j = 0; j < 8; ++j) hi[j] = (short)T[kq * 16 + 8 + j][cc];

    const int cR = c0 + cc;
    const int g1 = (k0 >> 3) + 2 * kq;                   // global k-chunk 0..63
    const int g2 = g1 + 1;
    const int d1 = (g1 >> 3) * 4096 + cR * 8 + ((g1 & 7) ^ (cR & 7));
    const int d2 = (g2 >> 3) * 4096 + cR * 8 + ((g2 & 7) ^ (cR & 7));
    short* wb = (short*)wcbt;
    *(short8*)(wb + d1 * 8) = lo;
    *(short8*)(wb + d2 * 8) = hi;
}

// ------------------------------------------------------------------ main ----
// 256 blocks x 512 threads (8 waves). Block owns rows [bm, bm+16) x ALL 512
// cols. B streamed in 8 chunks of [512 c][64 k] (64 KB), double-buffered,
// identity global_load_lds from pre-swizzled wcbt. A panel 16x512 in LDS.
// No atomics: pred rows exclusively owned, direct stores.
// Dynamic LDS: B0 @0 (64K), B1 @64K, A @128K (16K) = 144 KB. 1 block/CU.
__global__ __launch_bounds__(512) void main_kernel(
    const __hip_bfloat16* __restrict__ wcbt, const float* __restrict__ params,
    const float* __restrict__ x, const float* __restrict__ W1,
    const float* __restrict__ eps, float* __restrict__ out)
{
    extern __shared__ char smem[];
    char*  Ap = smem + 131072;                           // [16 r][512 k] bf16
    float* Cl = (float*)smem;                            // [512 c][20] (alias B0)
    float* P  = (float*)(smem + 40960);                  // partial 4 KB

    const int t = threadIdx.x;
    const int w = t >> 6, lane = t & 63;
    const int lane15 = lane & 15, quad = lane >> 4;
    const int ax7 = lane15 & 7;
    const int bm = blockIdx.x * 16;

    const char* wbase = (const char*)wcbt;

    // ---- issue B chunk 0 staging (8 x 16B per thread, identity copy)
    #pragma unroll
    for (int i = 0; i < 8; ++i)
        gl_lds16(wbase + (0 * 4096 + i * 512 + t) * 16, smem + i * 8192 + t * 16);

    // ---- A panel staging: thread -> (row t>>5, k-range (t&31)*16..+16)
    {
        const int r = t >> 5, seg = t & 31;
        const float* xrow = x + (bm + r) * D_P1 + seg * 16;
        #pragma unroll
        for (int c2 = 0; c2 < 2; ++c2) {
            int g  = seg * 2 + c2;
            int cs = (g & ~7) | ((g & 7) ^ (r & 7));
            short8 pk;
            #pragma unroll
            for (int j = 0; j < 8; ++j) pk[j] = (short)bf16b(xrow[c2 * 8 + j]);
            *(short8*)(Ap + r * 1024 + cs * 16) = pk;
        }
    }

    // ---- early independent loads (k=512 fixup, eps, wl)
    const float e = eps[lane];
    float xl[4];
    #pragma unroll
    for (int i = 0; i < 4; ++i)
        xl[i] = x[(bm + quad * 4 + i) * D_P1 + 512];
    float wl[4];
    #pragma unroll
    for (int s = 0; s < 4; ++s) {
        int c = (s < 2 ? 0 : 256) + w * 32 + (s & 1) * 16 + lane15;
        wl[s] = (c < 256) ? params[131072 + c]
                          : sqrtf(fmaxf(params[LEN_M + 131072 + (c - 256)], 0.0f) + 1e-6f);
    }

    // ---- fragment column byte-bases (c&7 == lane15&7 for all four)
    int cb[4];
    #pragma unroll
    for (int s = 0; s < 4; ++s)
        cb[s] = ((s < 2 ? 0 : 256) + w * 32 + (s & 1) * 16 + lane15) * 128;

    floatx4 acc[4];
    #pragma unroll
    for (int s = 0; s < 4; ++s) acc[s] = (floatx4){0.f, 0.f, 0.f, 0.f};

    __syncthreads();                                     // A + B chunk 0 ready

    for (int kc = 0; kc < 8; ++kc) {
        // prefetch next chunk into the other buffer
        if (kc < 7) {
            const int nb = (kc + 1) & 1;
            #pragma unroll
            for (int i = 0; i < 8; ++i)
                gl_lds16(wbase + ((kc + 1) * 4096 + i * 512 + t) * 16,
                         smem + nb * 65536 + i * 8192 + t * 16);
        }
        const char* Bb = smem + (kc & 1) * 65536;
        const char* Ab = Ap + lane15 * 1024 + kc * 128;
        #pragma unroll
        for (int kk = 0; kk < 2; ++kk) {
            const int off = ((kk * 4 + quad) ^ ax7) * 16;
            short8 a  = *(const short8*)(Ab + off);
            short8 b0 = *(const short8*)(Bb + cb[0] + off);
            short8 b1 = *(const short8*)(Bb + cb[1] + off);
            short8 b2 = *(const short8*)(Bb + cb[2] + off);
            short8 b3 = *(const short8*)(Bb + cb[3] + off);
            acc[0] = __builtin_amdgcn_mfma_f32_16x16x32_bf16(a, b0, acc[0], 0, 0, 0);
            acc[1] = __builtin_amdgcn_mfma_f32_16x16x32_bf16(a, b1, acc[1], 0, 0, 0);
            acc[2] = __builtin_amdgcn_mfma_f32_16x16x32_bf16(a, b2, acc[2], 0, 0, 0);
            acc[3] = __builtin_amdgcn_mfma_f32_16x16x32_bf16(a, b3, acc[3], 0, 0, 0);
        }
        __syncthreads();                                 // prefetch drained, buf safe
    }

    // ---- fixup k=512 + C -> LDS [c][20] (aliases B0; all B reads done)
    #pragma unroll
    for (int s = 0; s < 4; ++s) {
        int gc = (s < 2 ? 0 : 256) + w * 32 + (s & 1) * 16 + lane15;
        float4 o;
        o.x = acc[s][0] + xl[0] * wl[s];
        o.y = acc[s][1] + xl[1] * wl[s];
        o.z = acc[s][2] + xl[2] * wl[s];
        o.w = acc[s][3] + xl[3] * wl[s];
        *(float4*)&Cl[gc * 20 + quad * 4] = o;
    }
    __syncthreads();

    // ---- pred epilogue: lane = m; wave w: rows (w&3)*4..+4, h-half (w>>2)
    const int rq = (w & 3) * 4;
    const int hb = (w >> 2) * 128;
    v2f a01s = {0.f, 0.f}, a23s = {0.f, 0.f};
    const v2f e2 = {e, e}, z2 = {0.f, 0.f};

    #pragma unroll 4
    for (int hh = 0; hh < 128; ++hh) {
        const int h = hb + hh;
        const float w1h = W1[1 + h];
        const v2f w2 = {w1h, w1h};
        const float4 av = *(const float4*)&Cl[h * 20 + rq];
        const float4 bv = *(const float4*)&Cl[(256 + h) * 20 + rq];
        v2f a01 = {av.x, av.y}, a23 = {av.z, av.w};
        v2f b01 = {bv.x, bv.y}, b23 = {bv.z, bv.w};
        v2f t01 = __builtin_elementwise_max(__builtin_elementwise_fma(e2, b01, a01), z2);
        v2f t23 = __builtin_elementwise_max(__builtin_elementwise_fma(e2, b23, a23), z2);
        a01s = __builtin_elementwise_fma(t01, w2, a01s);
        a23s = __builtin_elementwise_fma(t23, w2, a23s);
    }

    // ---- combine h-halves (waves 4-7 -> LDS, waves 0-3 add + store)
    if (w >= 4) {
        float* p = P + (w - 4) * 256 + lane;
        p[0]   = a01s.x; p[64]  = a01s.y;
        p[128] = a23s.x; p[192] = a23s.y;
    }
    __syncthreads();
    if (w < 4) {
        const float b0 = W1[0];
        const float* p = P + w * 256 + lane;
        float* op = out + (bm + rq) * 64 + lane;
        op[0]   = a01s.x + p[0]   + b0;
        op[64]  = a01s.y + p[64]  + b0;
        op[128] = a23s.x + p[128] + b0;
        op[192] = a23s.y + p[192] + b0;
    }
}

// -------------------------------------------------------------- launch ------
extern "C" void kernel_launch(void* const* d_in, const int* in_sizes, int n_in,
                              void* d_out, int out_size, void* d_ws, size_t ws_size,
                              hipStream_t stream)
{
    const float* params = (const float*)d_in[0];
    const float* W1     = (const float*)d_in[1];
    const float* x      = (const float*)d_in[2];
    const float* eps    = (const float*)d_in[3];
    float* out = (float*)d_out;
    __hip_bfloat16* wcbt = (__hip_bfloat16*)d_ws;

    static bool attr_set = false;
    if (!attr_set) {
        hipFuncSetAttribute((const void*)main_kernel,
                            hipFuncAttributeMaxDynamicSharedMemorySize, 147456);
        attr_set = true;
    }

    prep_kernel<<<513 + 64, 256, 0, stream>>>(params, out, wcbt);
    main_kernel<<<256, 512, 147456, stream>>>(wcbt, params, x, W1, eps, out);
}